// Round 1
// 457.270 us; speedup vs baseline: 1.1425x; 1.1425x over previous
//
#include <hip/hip_runtime.h>
#include <math.h>

#define BATCH 256
#define NNODE 256
#define FIN   128
#define HID   48
#define DOUT  97

// packed transposed weight planes (ushort elements, per-plane offsets)
#define WOFF_DW0 0        // dW0^T [48][128]
#define WOFF_DW  6144     // dW[i]^T 4 x [48][64]
#define WOFF_UW  18432    // uW[i]^T 3 x [48][64]
#define WOFF_UWL 27648    // uWl^T  [112][64]
#define WTOT     34816    // per-plane stride

typedef __attribute__((ext_vector_type(8))) short bf16x8_t;
typedef __attribute__((ext_vector_type(4))) float f32x4_t;

__device__ inline unsigned short f2bf(float x) {
  unsigned u = __float_as_uint(x);
  u += 0x7fff + ((u >> 16) & 1);
  return (unsigned short)(u >> 16);
}
__device__ inline float bf2f(unsigned short h) {
  return __uint_as_float(((unsigned)h) << 16);
}

// ---------- fused A0 pass: bf16 convert + rowsum -> dinv (exact: 0/1 entries) ----------
__global__ __launch_bounds__(256) void k_prepA(const float* __restrict__ A,
                                               unsigned short* __restrict__ Abf,
                                               float* __restrict__ dinv, int rows) {
  int wid = (blockIdx.x * 256 + threadIdx.x) >> 6;
  int lane = threadIdx.x & 63;
  if (wid >= rows) return;
  const float4* rp = (const float4*)(A + (size_t)wid * 256);
  float4 v = rp[lane];
  unsigned long long pk = (unsigned long long)f2bf(v.x)
                        | ((unsigned long long)f2bf(v.y) << 16)
                        | ((unsigned long long)f2bf(v.z) << 32)
                        | ((unsigned long long)f2bf(v.w) << 48);
  *(unsigned long long*)(Abf + (size_t)wid * 256 + lane * 4) = pk;
  float s = v.x + v.y + v.z + v.w;
  #pragma unroll
  for (int o = 32; o > 0; o >>= 1) s += __shfl_down(s, o);
  if (lane == 0) dinv[wid] = 1.0f / sqrtf(s + 2.0f);
}

// ---------- dinv from bf16 integer adjacency (exact) ----------
__global__ __launch_bounds__(256) void k_dinv_bf(const unsigned short* __restrict__ Abf,
                                                 float* __restrict__ dinv, int n, int rows) {
  int wid = (blockIdx.x * 256 + threadIdx.x) >> 6;
  int lane = threadIdx.x & 63;
  if (wid >= rows) return;
  const unsigned short* row = Abf + (size_t)wid * n;
  float s = 0.f;
  for (int j = lane * 2; j < n; j += 128) {
    unsigned u = *(const unsigned*)(row + j);
    s += bf2f((unsigned short)(u & 0xffffu)) + bf2f((unsigned short)(u >> 16));
  }
  #pragma unroll
  for (int o = 32; o > 0; o >>= 1) s += __shfl_down(s, o);
  if (lane == 0) dinv[wid] = 1.0f / sqrtf(s + 2.0f);
}

// ---------- transpose + 3-plane split ALL weights (runs once, tiny) ----------
__global__ __launch_bounds__(256) void k_splitW3(const float* __restrict__ dW0,
                                                 const float* __restrict__ dW,
                                                 const float* __restrict__ uW,
                                                 const float* __restrict__ uWl,
                                                 unsigned short* __restrict__ Wp) {
  int idx = blockIdx.x * 256 + threadIdx.x;
  if (idx >= WTOT) return;
  float v;
  if (idx < WOFF_DW) {                   // dW0^T [48][128]
    int f = idx / 128, kk = idx - f * 128;
    v = dW0[kk * HID + f];
  } else if (idx < WOFF_UW) {            // dW[i]^T [48][64]
    int r = idx - WOFF_DW;
    int i = r / 3072; r -= i * 3072;
    int f = r / 64, kk = r - f * 64;
    v = (kk < HID) ? dW[((size_t)i * HID + kk) * HID + f] : 0.f;
  } else if (idx < WOFF_UWL) {           // uW[i]^T [48][64]
    int r = idx - WOFF_UW;
    int i = r / 3072; r -= i * 3072;
    int f = r / 64, kk = r - f * 64;
    v = (kk < HID) ? uW[((size_t)i * HID + kk) * HID + f] : 0.f;
  } else {                               // uWl^T [112][64]
    int r = idx - WOFF_UWL;
    int f = r / 64, kk = r - f * 64;
    v = (f < DOUT && kk < HID) ? uWl[(size_t)kk * DOUT + f] : 0.f;
  }
  unsigned short h = f2bf(v);
  float r1 = v - bf2f(h);
  unsigned short m = f2bf(r1);
  float r2 = r1 - bf2f(m);
  unsigned short l = f2bf(r2);
  Wp[idx] = h;
  Wp[idx + WTOT] = m;
  Wp[idx + 2 * WTOT] = l;
}

// ---------- wave-independent MFMA GEMM XW = X @ W, 3-plane split, NO LDS/barrier ----------
template<int KS2>   // K-steps of 32; KP = KS2*32
__global__ __launch_bounds__(256) void k_xws(const float* __restrict__ X,
                                             const unsigned short* __restrict__ Wp,
                                             float* __restrict__ XW,
                                             const float* __restrict__ dinv,
                                             unsigned short* __restrict__ Yth,
                                             unsigned short* __restrict__ Ytl,
                                             int K, int F, int Fpad, int nShift) {
  constexpr int KP = KS2 * 32;
  int mt = (blockIdx.x * 256 + threadIdx.x) >> 6;
  int lane = threadIdx.x & 63;
  int r = lane & 15, q = lane >> 4;
  const float* xr = X + ((long)mt * 16 + r) * K;
  bf16x8_t ah[KS2], am[KS2], al[KS2];
  #pragma unroll
  for (int ks = 0; ks < KS2; ks++) {
    int col0 = ks * 32 + q * 8;
    float v[8];
    if (col0 + 8 <= K) {
      float4 a = *(const float4*)(xr + col0);
      float4 b = *(const float4*)(xr + col0 + 4);
      v[0] = a.x; v[1] = a.y; v[2] = a.z; v[3] = a.w;
      v[4] = b.x; v[5] = b.y; v[6] = b.z; v[7] = b.w;
    } else {
      #pragma unroll
      for (int j = 0; j < 8; j++) v[j] = (col0 + j < K) ? xr[col0 + j] : 0.f;
    }
    #pragma unroll
    for (int j = 0; j < 8; j++) {
      unsigned short h = f2bf(v[j]);
      float r1 = v[j] - bf2f(h);
      unsigned short m = f2bf(r1);
      float r2 = r1 - bf2f(m);
      unsigned short l = f2bf(r2);
      ah[ks][j] = (short)h;
      am[ks][j] = (short)m;
      al[ks][j] = (short)l;
    }
  }
  long row0 = (long)mt * 16 + q * 4;
  float4 dv4 = {0.f, 0.f, 0.f, 0.f};
  long ytBase = 0;
  if (Yth) {
    dv4 = *(const float4*)(dinv + row0);
    int bb = (int)(row0 >> nShift);
    int jj = (int)(row0 & ((1 << nShift) - 1));
    ytBase = (long)bb * Fpad;
    ytBase = ytBase << nShift;
    ytBase += jj;
  }
  int nFT = Fpad >> 4;
  for (int ft = 0; ft < nFT; ft++) {
    int fl = ft * 16 + r;
    const unsigned short* wb = Wp + (size_t)fl * KP + q * 8;
    f32x4_t acc = {0.f, 0.f, 0.f, 0.f};
    #pragma unroll
    for (int ks = 0; ks < KS2; ks++) {
      bf16x8_t bh = *(const bf16x8_t*)(wb + ks * 32);
      bf16x8_t bm = *(const bf16x8_t*)(wb + WTOT + ks * 32);
      bf16x8_t bl = *(const bf16x8_t*)(wb + 2 * WTOT + ks * 32);
      acc = __builtin_amdgcn_mfma_f32_16x16x32_bf16(ah[ks], bh, acc, 0, 0, 0);
      acc = __builtin_amdgcn_mfma_f32_16x16x32_bf16(ah[ks], bm, acc, 0, 0, 0);
      acc = __builtin_amdgcn_mfma_f32_16x16x32_bf16(am[ks], bh, acc, 0, 0, 0);
      acc = __builtin_amdgcn_mfma_f32_16x16x32_bf16(am[ks], bm, acc, 0, 0, 0);
      acc = __builtin_amdgcn_mfma_f32_16x16x32_bf16(ah[ks], bl, acc, 0, 0, 0);
      acc = __builtin_amdgcn_mfma_f32_16x16x32_bf16(al[ks], bh, acc, 0, 0, 0);
    }
    int f = fl;
    if (f < F) {
      if (XW) {
        #pragma unroll
        for (int reg = 0; reg < 4; reg++) XW[(row0 + reg) * F + f] = acc[reg];
      }
      if (Yth) {
        float dvv[4] = {dv4.x, dv4.y, dv4.z, dv4.w};
        unsigned long long hpk = 0, lpk = 0;
        #pragma unroll
        for (int reg = 0; reg < 4; reg++) {
          float v = dvv[reg] * acc[reg];
          unsigned short hi = f2bf(v);
          unsigned short lo = f2bf(v - bf2f(hi));
          hpk |= ((unsigned long long)hi) << (16 * reg);
          lpk |= ((unsigned long long)lo) << (16 * reg);
        }
        long o = ytBase + ((long)f << nShift);
        *(unsigned long long*)(Yth + o) = hpk;
        *(unsigned long long*)(Ytl + o) = lpk;
      }
    }
  }
}

// ---------- LDS-free fused GCN: ITP it-tiles per wave, A in regs ----------
template<int KS, int ITP>
__global__ __launch_bounds__(256) void k_gcn2(
    const unsigned short* __restrict__ Abf, const float* __restrict__ dinv,
    const unsigned short* __restrict__ Yth, const unsigned short* __restrict__ Ytl,
    const float* __restrict__ bias, float* __restrict__ out,
    int F, int Fpad, int dorelu) {
  constexpr int n = KS * 32;
  int b = blockIdx.x & (BATCH - 1);
  int sub = blockIdx.x >> 8;
  int wave = threadIdx.x >> 6, lane = threadIdx.x & 63;
  int r = lane & 15, q = lane >> 4;
  const float* dv = dinv + (size_t)b * n;
  int itBase = (sub * 4 + wave) * ITP;
  bf16x8_t af[ITP][KS];
  #pragma unroll
  for (int l = 0; l < ITP; l++) {
    const unsigned short* ap = Abf + ((size_t)b * n + (itBase + l) * 16 + r) * n + q * 8;
    #pragma unroll
    for (int ks = 0; ks < KS; ks++) af[l][ks] = *(const bf16x8_t*)(ap + ks * 32);
  }
  float di[ITP][4];
  #pragma unroll
  for (int l = 0; l < ITP; l++) {
    int i0 = (itBase + l) * 16 + q * 4;
    #pragma unroll
    for (int reg = 0; reg < 4; reg++) di[l][reg] = dv[i0 + reg];
  }
  int nFT = Fpad >> 4;
  for (int ft = 0; ft < nFT; ft++) {
    int fl = ft * 16 + r;
    const unsigned short* yrowh = Yth + ((size_t)b * Fpad + fl) * n;
    const unsigned short* yrowl = Ytl + ((size_t)b * Fpad + fl) * n;
    f32x4_t acc[ITP];
    #pragma unroll
    for (int l = 0; l < ITP; l++) acc[l] = (f32x4_t){0.f, 0.f, 0.f, 0.f};
    #pragma unroll
    for (int ks = 0; ks < KS; ks++) {
      bf16x8_t bh = *(const bf16x8_t*)(yrowh + q * 8 + ks * 32);
      bf16x8_t bl = *(const bf16x8_t*)(yrowl + q * 8 + ks * 32);
      #pragma unroll
      for (int l = 0; l < ITP; l++) {
        acc[l] = __builtin_amdgcn_mfma_f32_16x16x32_bf16(af[l][ks], bh, acc[l], 0, 0, 0);
        acc[l] = __builtin_amdgcn_mfma_f32_16x16x32_bf16(af[l][ks], bl, acc[l], 0, 0, 0);
      }
    }
    if (fl < F) {
      float bf = bias[fl];
      #pragma unroll
      for (int l = 0; l < ITP; l++) {
        int i0 = (itBase + l) * 16 + q * 4;
        unsigned long long hq = *(const unsigned long long*)(yrowh + i0);
        unsigned long long lq = *(const unsigned long long*)(yrowl + i0);
        #pragma unroll
        for (int reg = 0; reg < 4; reg++) {
          float yv = bf2f((unsigned short)(hq >> (16 * reg)))
                   + bf2f((unsigned short)(lq >> (16 * reg)));
          float v = di[l][reg] * acc[l][reg] + 2.f * di[l][reg] * yv + bf;
          if (dorelu) v = fmaxf(v, 0.f);
          out[((size_t)b * n + i0 + reg) * F + fl] = v;
        }
      }
    }
  }
}

// ---------- final-GCN column 96 (ranking scores): matvec per node ----------
__global__ __launch_bounds__(256) void k_hcol(const unsigned short* __restrict__ Abf,
                                              const float* __restrict__ dinv,
                                              const unsigned short* __restrict__ Yth,
                                              const unsigned short* __restrict__ Ytl,
                                              float* __restrict__ col) {
  int gw = blockIdx.x * 4 + (threadIdx.x >> 6);   // gw = b*256 + i
  int lane = threadIdx.x & 63;
  int b = gw >> 8, i = gw & 255;
  const unsigned short* ar = Abf + (size_t)gw * 256;
  const unsigned short* yh = Yth + ((size_t)b * 112 + 96) * 256;
  const unsigned short* yl = Ytl + ((size_t)b * 112 + 96) * 256;
  unsigned long long a4 = *(const unsigned long long*)(ar + lane * 4);
  unsigned long long h4 = *(const unsigned long long*)(yh + lane * 4);
  unsigned long long l4 = *(const unsigned long long*)(yl + lane * 4);
  float s = 0.f;
  #pragma unroll
  for (int e = 0; e < 4; e++) {
    float av = bf2f((unsigned short)(a4 >> (16 * e)));
    float yv = bf2f((unsigned short)(h4 >> (16 * e)))
             + bf2f((unsigned short)(l4 >> (16 * e)));
    s += av * yv;
  }
  #pragma unroll
  for (int o = 32; o > 0; o >>= 1) s += __shfl_down(s, o);
  if (lane == 0) {
    float d = dinv[gw];
    float yv = bf2f(yh[i]) + bf2f(yl[i]);
    col[gw] = d * s + 2.f * d * yv;
  }
}

// ---------- exact top-30 rank over col-96 scores ----------
__global__ __launch_bounds__(256) void k_hsel(const float* __restrict__ col,
                                              int* __restrict__ ord) {
  int b = blockIdx.x, t = threadIdx.x;
  __shared__ float s[256];
  s[t] = col[(size_t)b * 256 + t];
  __syncthreads();
  float v = s[t];
  int r = 0;
  for (int j = 0; j < 256; j++) {
    float u = s[j];
    r += (u > v) || (u == v && j < t);
  }
  if (r < 30) ord[(size_t)b * 30 + r] = t;
}

// ---------- final-GCN rows for top-30 nodes only (gathered-A MFMA) ----------
__global__ __launch_bounds__(256) void k_hrow(const unsigned short* __restrict__ Abf,
                                              const float* __restrict__ dinv,
                                              const int* __restrict__ ord,
                                              const unsigned short* __restrict__ Yth,
                                              const unsigned short* __restrict__ Ytl,
                                              const float* __restrict__ ubl,
                                              float* __restrict__ sp) {
  int b = blockIdx.x;
  int wave = threadIdx.x >> 6, lane = threadIdx.x & 63;
  int it = wave & 1, fh = wave >> 1;
  int r = lane & 15, q = lane >> 4;
  const int* po = ord + (size_t)b * 30;
  int ari = it * 16 + r;
  int arow = po[ari < 30 ? ari : 0];
  const unsigned short* ap = Abf + ((size_t)b * 256 + arow) * 256 + q * 8;
  bf16x8_t af[8];
  #pragma unroll
  for (int ks = 0; ks < 8; ks++) af[ks] = *(const bf16x8_t*)(ap + ks * 32);
  int ftBeg = fh * 4, ftEnd = fh ? 7 : 4;
  for (int ft = ftBeg; ft < ftEnd; ft++) {
    int fl = ft * 16 + r;
    const unsigned short* yrowh = Yth + ((size_t)b * 112 + fl) * 256;
    const unsigned short* yrowl = Ytl + ((size_t)b * 112 + fl) * 256;
    f32x4_t acc = {0.f, 0.f, 0.f, 0.f};
    #pragma unroll
    for (int ks = 0; ks < 8; ks++) {
      bf16x8_t bh = *(const bf16x8_t*)(yrowh + q * 8 + ks * 32);
      bf16x8_t bl = *(const bf16x8_t*)(yrowl + q * 8 + ks * 32);
      acc = __builtin_amdgcn_mfma_f32_16x16x32_bf16(af[ks], bh, acc, 0, 0, 0);
      acc = __builtin_amdgcn_mfma_f32_16x16x32_bf16(af[ks], bl, acc, 0, 0, 0);
    }
    if (fl < DOUT) {
      float bf = ubl[fl];
      #pragma unroll
      for (int reg = 0; reg < 4; reg++) {
        int rowidx = it * 16 + q * 4 + reg;
        if (rowidx < 30) {
          int node = po[rowidx];
          float d = dinv[(size_t)b * 256 + node];
          float yv = bf2f(yrowh[node]) + bf2f(yrowl[node]);
          sp[((size_t)b * 30 + rowidx) * DOUT + fl] = d * acc[reg] + 2.f * d * yv + bf;
        }
      }
    }
  }
}

// ---------- MFMA augment via M=A+I trick (EXACT), XCD-swizzled ----------
__global__ __launch_bounds__(256) void k_aug_mfma(const unsigned short* __restrict__ Abf,
                                                  const int* __restrict__ perm,
                                                  float* __restrict__ Ap,
                                                  unsigned short* __restrict__ Apbf,
                                                  int n, int k) {
  int kt = k >> 4;
  int inner = blockIdx.x & 255;
  int slot = blockIdx.x >> 8;
  int b = ((inner & 7) << 5) | (inner >> 3);
  int wave = threadIdx.x >> 6, lane = threadIdx.x & 63;
  int tile = slot * 4 + wave;
  int it = tile / kt, ft = tile - it * kt;
  int r = lane & 15, q = lane >> 4;
  const int* pm = perm + (size_t)b * k;
  int rowA = pm[it * 16 + r];
  int rowB = pm[ft * 16 + r];
  const unsigned short* Ab = Abf + (size_t)b * n * n;
  const unsigned short* pa = Ab + (size_t)rowA * n + q * 8;
  const unsigned short* pb = Ab + (size_t)rowB * n + q * 8;
  f32x4_t acc = {0.f, 0.f, 0.f, 0.f};
  for (int k0 = 0; k0 < n; k0 += 32) {
    bf16x8_t a  = *(const bf16x8_t*)(pa + k0);
    bf16x8_t bv = *(const bf16x8_t*)(pb + k0);
    int daA = rowA - k0 - q * 8;
    int daB = rowB - k0 - q * 8;
    #pragma unroll
    for (int e = 0; e < 8; e++) {
      if (daA == e) a[e] = (short)0x3F80;   // bf16(1.0)
      if (daB == e) bv[e] = (short)0x3F80;
    }
    acc = __builtin_amdgcn_mfma_f32_16x16x32_bf16(a, bv, acc, 0, 0, 0);
  }
  int c = ft * 16 + r;
  #pragma unroll
  for (int reg = 0; reg < 4; reg++) {
    int rr = it * 16 + q * 4 + reg;
    float v = acc[reg];
    if (rr == c) v = 0.f;
    if (Ap)   Ap[((size_t)b * k + rr) * k + c] = v;
    if (Apbf) Apbf[((size_t)b * k + rr) * k + c] = f2bf(v);
  }
}

// ---------- fused pooling: score + exact top-k rank + gather ----------
__global__ __launch_bounds__(256) void k_pool(const float* __restrict__ H,
                                              const float* __restrict__ p,
                                              int* __restrict__ perm,
                                              float* __restrict__ Hout,
                                              int n, int k) {
  int b = blockIdx.x, t = threadIdx.x;
  __shared__ float s[256];
  __shared__ int sord[128];
  float pn = 0.f;
  #pragma unroll
  for (int j = 0; j < HID; j++) pn += p[j] * p[j];
  if (t < n) {
    const float* hr = H + ((size_t)b * n + t) * HID;
    float acc = 0.f;
    #pragma unroll
    for (int j = 0; j < HID; j++) acc += hr[j] * p[j];
    s[t] = tanhf(acc / sqrtf(pn));
  }
  __syncthreads();
  if (t < n) {
    float v = s[t];
    int r = 0;
    for (int j = 0; j < n; j++) {
      float u = s[j];
      r += (u > v) || (u == v && j < t);
    }
    if (r < k) { perm[(size_t)b * k + r] = t; sord[r] = t; }
  }
  __syncthreads();
  for (int idx = t; idx < k * HID; idx += 256) {
    int r = idx / HID, f = idx - r * HID;
    int pi = sord[r];
    Hout[((size_t)b * k + r) * HID + f] = H[((size_t)b * n + pi) * HID + f] * s[pi];
  }
}

// ---------- decoder scatter-add (outer level only) ----------
__global__ __launch_bounds__(256) void k_scatter(const int* __restrict__ perm,
                                                 const float* __restrict__ Hsrc,
                                                 float* __restrict__ Hdst,
                                                 int n, int k, int total) {
  int idx = blockIdx.x * 256 + threadIdx.x;
  if (idx >= total) return;
  int f = idx % HID;
  int r = (idx / HID) % k;
  int b = idx / (HID * k);
  int pi = perm[(size_t)b * k + r];
  Hdst[((size_t)b * n + pi) * HID + f] += Hsrc[idx];
}

// ---------- fused head (reads precomputed sp[b][30][97]) ----------
__global__ __launch_bounds__(256) void k_head2(const float* __restrict__ spg,
                                               const float* __restrict__ c1W,
                                               const float* __restrict__ c1b,
                                               const float* __restrict__ c2W,
                                               const float* __restrict__ c2b,
                                               const float* __restrict__ oW,
                                               const float* __restrict__ ob,
                                               float* __restrict__ out) {
  int b = blockIdx.x, t = threadIdx.x;
  __shared__ float sp[30 * 97];
  __shared__ float y1[16 * 30];
  __shared__ float yp[16 * 15];
  __shared__ float yc[32 * 11];
  const float* spb = spg + (size_t)b * 30 * 97;
  for (int idx = t; idx < 30 * 97; idx += 256) sp[idx] = spb[idx];
  __syncthreads();
  for (int idx = t; idx < 16 * 30; idx += 256) {
    int c = idx / 30, kk = idx - c * 30;
    float a = c1b[c];
    for (int d = 0; d < 97; d++) a += sp[kk * 97 + d] * c1W[c * 97 + d];
    y1[c * 30 + kk] = fmaxf(a, 0.f);
  }
  __syncthreads();
  for (int idx = t; idx < 16 * 15; idx += 256) {
    int c = idx / 15, t2 = idx - c * 15;
    yp[idx] = fmaxf(y1[c * 30 + 2 * t2], y1[c * 30 + 2 * t2 + 1]);
  }
  __syncthreads();
  for (int idx = t; idx < 32 * 11; idx += 256) {
    int o = idx / 11, t3 = idx - o * 11;
    float a = c2b[o];
    for (int i2 = 0; i2 < 16; i2++)
      for (int w = 0; w < 5; w++)
        a += yp[i2 * 15 + t3 + w] * c2W[(o * 16 + i2) * 5 + w];
    yc[o * 11 + t3] = fmaxf(a, 0.f);
  }
  __syncthreads();
  if (t < 32) {
    float a = ob[t];
    for (int q = 0; q < 352; q++) a += yc[q] * oW[q * 32 + t];
    out[(size_t)b * 32 + t] = fmaxf(a, 0.f);
  }
}

// ========== fused inner U-Net (encoder lvl1..3 + decoder j=3..2 + scatter into H1) ==========
// One block per batch (grid=256 -> 1 block/CU), 512 threads, exact fp32, all n<=64 state
// in LDS. Replaces 22 launch-overhead-bound dispatches. LDS = 65,280 B (padded strides
// 65/33/17 and bf16 stage stride 132 avoid 32-way bank conflicts on gathered-row reads).

__device__ inline void xw_dphase(const float* hin, const float* W, const float* dv,
                                 float* xwd, int n, int t) {
  // xwd[j*48+f] = dv[j] * sum_g hin[j*48+g] * W[g*48+f]
  for (int idx = t; idx < n * 48; idx += 512) {
    int j = idx / 48, f = idx - j * 48;
    const float* hr = hin + j * 48;
    float a = 0.f;
    #pragma unroll
    for (int g = 0; g < 48; g++) a += hr[g] * W[g * 48 + f];
    xwd[idx] = dv[j] * a;
  }
}

__device__ inline void anxw_phase(const float* A, int lda, const float* xwd,
                                  const float* dv, const float* bias,
                                  float* hout, int n, int t) {
  // hout[i][f] = relu(d_i * sum_j A[i][j]*xwd[j][f] + 2*d_i*xwd[i][f] + bias[f])
  for (int idx = t; idx < n * 48; idx += 512) {
    int i = idx / 48, f = idx - i * 48;
    const float* ar = A + i * lda;
    float acc = 0.f;
    #pragma unroll 4
    for (int j = 0; j < n; j++) acc += ar[j] * xwd[j * 48 + f];
    float di = dv[i];
    float v = di * acc + 2.f * di * xwd[i * 48 + f] + bias[f];
    hout[idx] = fmaxf(v, 0.f);
  }
}

__device__ inline void pool_phase(const float* h, const float* p, int n, int k,
                                  float* sS, int* perm, float* hin, int t) {
  if (t < n) {
    const float* hr = h + t * 48;
    float pn = 0.f, acc = 0.f;
    #pragma unroll
    for (int g = 0; g < 48; g++) { pn += p[g] * p[g]; acc += hr[g] * p[g]; }
    sS[t] = tanhf(acc / sqrtf(pn));
  }
  __syncthreads();
  if (t < n) {
    float v = sS[t]; int r = 0;
    for (int j = 0; j < n; j++) { float u = sS[j]; r += (u > v) || (u == v && j < t); }
    if (r < k) perm[r] = t;
  }
  __syncthreads();
  for (int idx = t; idx < k * 48; idx += 512) {
    int r = idx / 48, g = idx - r * 48;
    int pi = perm[r];
    hin[idx] = h[pi * 48 + g] * sS[pi];
  }
  __syncthreads();
}

__device__ inline void aug_phase(const float* A, int lda, const int* perm,
                                 float* Ao, int ldo, float* dout, int n, int k, int t) {
  // Ao[r][c] = dot(A_row_pr, A_row_pc) + 2*A[pr][pc]  (A symmetric); diag = 0
  for (int idx = t; idx < k * k; idx += 512) {
    int r = idx / k, c = idx - r * k;
    int pr = perm[r], pc = perm[c];
    const float* ra = A + pr * lda;
    const float* rc = A + pc * lda;
    float acc = 0.f;
    #pragma unroll 4
    for (int j = 0; j < n; j++) acc += ra[j] * rc[j];
    float v = acc + 2.f * ra[pc];
    Ao[r * ldo + c] = (r == c) ? 0.f : v;
  }
  __syncthreads();
  if (t < k) {
    const float* ar = Ao + t * ldo;
    float s = 0.f;
    for (int j = 0; j < k; j++) s += ar[j];
    dout[t] = 1.0f / sqrtf(s + 2.0f);
  }
  __syncthreads();
}

__device__ inline void scat_phase(const int* perm, const float* src, float* dst,
                                  int k, int t) {
  for (int idx = t; idx < k * 48; idx += 512) {
    int r = idx / 48, g = idx - r * 48;
    dst[perm[r] * 48 + g] += src[idx];
  }
  __syncthreads();
}

__global__ __launch_bounds__(512) void k_inner(const unsigned short* __restrict__ Abf1g,
                                               float* __restrict__ H1g,
                                               const float* __restrict__ dW,
                                               const float* __restrict__ dbv,
                                               const float* __restrict__ pp,
                                               const float* __restrict__ uW,
                                               const float* __restrict__ ub) {
  int b = blockIdx.x, t = threadIdx.x;
  const unsigned short* A1 = Abf1g + (size_t)b * 128 * 128;
  float* H1 = H1g + (size_t)b * 128 * 48;

  __shared__ float sS[128];
  __shared__ int   sP2[64], sP3[32], sP4[16];
  __shared__ float sD2[64], sD3[32], sD4[16];
  __shared__ float sA2[64 * 65];
  __shared__ float sA3[32 * 33];
  __shared__ float sH2[64 * 48];   // xs[2] residual, updated in place by decoder
  __shared__ float sH3[32 * 48];   // xs[3] residual
  __shared__ float sU[6144];       // 24576 B union scratch
  float* hin = sU;                          // pooled input [n][48], n<=64
  float* sXW = sU + 3072;                   // d-scaled XW [n][48]
  float* sH4 = sU + 1536;                   // [16][48] (free slot during lvl3/dec3)
  float* sA4 = sU + 2304;                   // [16][17]
  unsigned short* sG = (unsigned short*)sU; // [64][132] bf16 aug1 staging (dies first)

  // ===== encoder level 1: pool scores + rank over H1 (n=128 -> k=64) =====
  {
    const float* p = pp + 48;
    if (t < 128) {
      const float* hr = H1 + t * 48;
      float pn = 0.f, acc = 0.f;
      #pragma unroll
      for (int g = 0; g < 48; g++) { pn += p[g] * p[g]; acc += hr[g] * p[g]; }
      sS[t] = tanhf(acc / sqrtf(pn));
    }
    __syncthreads();
    if (t < 128) {
      float v = sS[t]; int r = 0;
      for (int j = 0; j < 128; j++) { float u = sS[j]; r += (u > v) || (u == v && j < t); }
      if (r < 64) sP2[r] = t;
    }
    __syncthreads();
  }
  // ===== aug1: stage gathered bf16 A1 rows, A2 via M=A+I dot trick (fp32 exact) =====
  for (int idx = t; idx < 64 * 64; idx += 512) {
    int r = idx >> 6, q = idx & 63;
    ((unsigned*)(sG + r * 132))[q] = ((const unsigned*)(A1 + sP2[r] * 128))[q];
  }
  __syncthreads();
  for (int idx = t; idx < 64 * 64; idx += 512) {
    int r = idx >> 6, c = idx & 63;
    const unsigned* ua = (const unsigned*)(sG + r * 132);
    const unsigned* uc = (const unsigned*)(sG + c * 132);
    float acc = 0.f;
    #pragma unroll 4
    for (int k = 0; k < 64; k++) {
      unsigned a = ua[k], cc = uc[k];
      acc += bf2f((unsigned short)(a & 0xffffu)) * bf2f((unsigned short)(cc & 0xffffu))
           + bf2f((unsigned short)(a >> 16)) * bf2f((unsigned short)(cc >> 16));
    }
    float v = acc + 2.f * bf2f(sG[r * 132 + sP2[c]]);
    sA2[r * 65 + c] = (r == c) ? 0.f : v;
  }
  __syncthreads();
  // D2 + gather pooled input (independent writes, one phase)
  if (t < 64) {
    const float* ar = sA2 + t * 65;
    float s = 0.f;
    for (int j = 0; j < 64; j++) s += ar[j];
    sD2[t] = 1.0f / sqrtf(s + 2.0f);
  }
  for (int idx = t; idx < 64 * 48; idx += 512) {
    int r = idx / 48, g = idx - r * 48;
    int pi = sP2[r];
    hin[idx] = H1[pi * 48 + g] * sS[pi];
  }
  __syncthreads();
  // encoder GCN level 1 (dW[1], db[1]) -> sH2 (= xs[2])
  xw_dphase(hin, dW + 2304, sD2, sXW, 64, t);
  __syncthreads();
  anxw_phase(sA2, 65, sXW, sD2, dbv + 48, sH2, 64, t);
  __syncthreads();

  // ===== encoder level 2 (64 -> 32): dW[2], db[2], pool_p[2] =====
  pool_phase(sH2, pp + 96, 64, 32, sS, sP3, hin, t);
  aug_phase(sA2, 65, sP3, sA3, 33, sD3, 64, 32, t);
  xw_dphase(hin, dW + 2 * 2304, sD3, sXW, 32, t);
  __syncthreads();
  anxw_phase(sA3, 33, sXW, sD3, dbv + 96, sH3, 32, t);
  __syncthreads();

  // ===== encoder level 3 (32 -> 16): dW[3], db[3], pool_p[3] =====
  pool_phase(sH3, pp + 144, 32, 16, sS, sP4, hin, t);
  aug_phase(sA3, 33, sP4, sA4, 17, sD4, 32, 16, t);
  xw_dphase(hin, dW + 3 * 2304, sD4, sXW, 16, t);
  __syncthreads();
  anxw_phase(sA4, 17, sXW, sD4, dbv + 144, sH4, 16, t);
  __syncthreads();

  // ===== decoder j=3: sH3 += up(sH4); GCN(uW[0], ub[0], A3/D3) =====
  scat_phase(sP4, sH4, sH3, 16, t);
  xw_dphase(sH3, uW, sD3, sXW, 32, t);
  __syncthreads();
  anxw_phase(sA3, 33, sXW, sD3, ub, sH3, 32, t);
  __syncthreads();

  // ===== decoder j=2: sH2 += up(sH3); GCN(uW[1], ub[1], A2/D2) =====
  scat_phase(sP3, sH3, sH2, 32, t);
  xw_dphase(sH2, uW + 2304, sD2, sXW, 64, t);
  __syncthreads();
  anxw_phase(sA2, 65, sXW, sD2, ub + 48, sH2, 64, t);
  __syncthreads();

  // ===== final: H1 (global) += up(sH2) via P2 =====
  for (int idx = t; idx < 64 * 48; idx += 512) {
    int r = idx / 48, g = idx - r * 48;
    H1[sP2[r] * 48 + g] += sH2[idx];
  }
}

extern "C" void kernel_launch(void* const* d_in, const int* in_sizes, int n_in,
                              void* d_out, int out_size, void* d_ws, size_t ws_size,
                              hipStream_t stream) {
  const float* x   = (const float*)d_in[0];
  const float* A0  = (const float*)d_in[1];
  const float* dW0 = (const float*)d_in[2];
  const float* db0 = (const float*)d_in[3];
  const float* dW  = (const float*)d_in[4];
  const float* dbv = (const float*)d_in[5];
  const float* pp  = (const float*)d_in[6];
  const float* uW  = (const float*)d_in[7];
  const float* ub  = (const float*)d_in[8];
  const float* uWl = (const float*)d_in[9];
  const float* ubl = (const float*)d_in[10];
  const float* c1W = (const float*)d_in[11];
  const float* c1b = (const float*)d_in[12];
  const float* c2W = (const float*)d_in[13];
  const float* c2b = (const float*)d_in[14];
  const float* oW  = (const float*)d_in[15];
  const float* ob  = (const float*)d_in[16];
  float* out = (float*)d_out;

  float* base = (float*)d_ws;
  size_t off = 0;
  auto alloc = [&](size_t nel) { nel = (nel + 3) & ~(size_t)3; float* p = base + off; off += nel; return p; };
  float* H0 = alloc((size_t)BATCH * 256 * HID);
  float* H1 = alloc((size_t)BATCH * 128 * HID);
  float* D0 = alloc((size_t)BATCH * 256);
  float* D1 = alloc((size_t)BATCH * 128);
  float* COL = alloc((size_t)BATCH * 256);
  float* SP  = alloc((size_t)BATCH * 30 * 97);
  int* P1 = (int*)alloc((size_t)BATCH * 128);
  int* ORD = (int*)alloc((size_t)BATCH * 30 + 2);
  unsigned short* Abf0 = (unsigned short*)alloc((size_t)BATCH * 256 * 256 / 2);
  unsigned short* Abf1 = (unsigned short*)alloc((size_t)BATCH * 128 * 128 / 2);
  unsigned short* Yth  = (unsigned short*)alloc((size_t)BATCH * 112 * 256 / 2);
  unsigned short* Ytl  = (unsigned short*)alloc((size_t)BATCH * 112 * 256 / 2);
  unsigned short* Wp   = (unsigned short*)alloc((size_t)3 * WTOT / 2 + 4);

  // ---- prologue ----
  k_prepA<<<BATCH * 256 / 4, 256, 0, stream>>>(A0, Abf0, D0, BATCH * 256);
  k_splitW3<<<(WTOT + 255) / 256, 256, 0, stream>>>(dW0, dW, uW, uWl, Wp);

  // ---- first GCN (n=256) ----
  k_xws<4><<<BATCH * 256 / 64, 256, 0, stream>>>(x, Wp + WOFF_DW0, nullptr,
                                                 D0, Yth, Ytl, FIN, HID, 48, 8);
  k_gcn2<8, 2><<<BATCH * 2, 256, 0, stream>>>(Abf0, D0, Yth, Ytl, db0, H0, HID, 48, 1);

  // ---- encoder level 0 (256 -> 128, MFMA path) ----
  k_pool<<<BATCH, 256, 0, stream>>>(H0, pp, P1, H1, 256, 128);
  k_aug_mfma<<<16 * 256, 256, 0, stream>>>(Abf0, P1, nullptr, Abf1, 256, 128);
  k_dinv_bf<<<BATCH * 128 / 4, 256, 0, stream>>>(Abf1, D1, 128, BATCH * 128);
  k_xws<2><<<BATCH * 128 / 64, 256, 0, stream>>>(H1, Wp + WOFF_DW, nullptr,
                                                 D1, Yth, Ytl, HID, HID, 48, 7);
  k_gcn2<4, 1><<<BATCH * 2, 256, 0, stream>>>(Abf1, D1, Yth, Ytl, dbv, H1, HID, 48, 1);

  // ---- fused inner U: enc lvl1..3 + dec j=3..2 + scatter into H1 (was 22 launches) ----
  k_inner<<<BATCH, 512, 0, stream>>>(Abf1, H1, dW, dbv, pp, uW, ub);

  // ---- decoder j=1 (n=128, MFMA path, uW[2], ub[2]) ----
  k_xws<2><<<BATCH * 128 / 64, 256, 0, stream>>>(H1, Wp + WOFF_UW + 2 * 3072, nullptr,
                                                 D1, Yth, Ytl, HID, HID, 48, 7);
  k_gcn2<4, 1><<<BATCH * 2, 256, 0, stream>>>(Abf1, D1, Yth, Ytl, ub + 2 * HID,
                                              H1, HID, 48, 1);

  // ---- decoder j=0: scatter + final GCN (col-96 ranking + top-30 rows) ----
  k_scatter<<<(BATCH * 128 * HID + 255) / 256, 256, 0, stream>>>(P1, H1, H0,
                                                                 256, 128, BATCH * 128 * HID);
  k_xws<2><<<BATCH * 256 / 64, 256, 0, stream>>>(H0, Wp + WOFF_UWL, nullptr,
                                                 D0, Yth, Ytl, HID, DOUT, 112, 8);
  k_hcol<<<BATCH * 256 / 4, 256, 0, stream>>>(Abf0, D0, Yth, Ytl, COL);
  k_hsel<<<BATCH, 256, 0, stream>>>(COL, ORD);
  k_hrow<<<BATCH, 256, 0, stream>>>(Abf0, D0, ORD, Yth, Ytl, ubl, SP);

  // ---- fused head ----
  k_head2<<<BATCH, 256, 0, stream>>>(SP, c1W, c1b, c2W, c2b, oW, ob, out);
}

// Round 2
// 422.566 us; speedup vs baseline: 1.2363x; 1.0821x over previous
//
#include <hip/hip_runtime.h>
#include <math.h>

#define BATCH 256
#define NNODE 256
#define FIN   128
#define HID   48
#define DOUT  97

// packed transposed weight planes (ushort elements, per-plane offsets)
#define WOFF_DW0 0        // dW0^T [48][128]
#define WOFF_DW  6144     // dW[i]^T 4 x [48][64]
#define WOFF_UW  18432    // uW[i]^T 3 x [48][64]
#define WOFF_UWL 27648    // uWl^T  [112][64]
#define WTOT     34816    // per-plane stride

typedef __attribute__((ext_vector_type(8))) short bf16x8_t;
typedef __attribute__((ext_vector_type(4))) float f32x4_t;

__device__ inline unsigned short f2bf(float x) {
  unsigned u = __float_as_uint(x);
  u += 0x7fff + ((u >> 16) & 1);
  return (unsigned short)(u >> 16);
}
__device__ inline float bf2f(unsigned short h) {
  return __uint_as_float(((unsigned)h) << 16);
}

template<int L> __device__ inline float grp_sum(float v) {
  #pragma unroll
  for (int o = L >> 1; o > 0; o >>= 1) v += __shfl_xor(v, o);
  return v;
}
template<int L> __device__ inline int grp_isum(int v) {
  #pragma unroll
  for (int o = L >> 1; o > 0; o >>= 1) v += __shfl_xor(v, o);
  return v;
}

// ---------- fused A0 pass: bf16 convert + rowsum -> dinv (exact: 0/1 entries) ----------
__global__ __launch_bounds__(256) void k_prepA(const float* __restrict__ A,
                                               unsigned short* __restrict__ Abf,
                                               float* __restrict__ dinv, int rows) {
  int wid = (blockIdx.x * 256 + threadIdx.x) >> 6;
  int lane = threadIdx.x & 63;
  if (wid >= rows) return;
  const float4* rp = (const float4*)(A + (size_t)wid * 256);
  float4 v = rp[lane];
  unsigned long long pk = (unsigned long long)f2bf(v.x)
                        | ((unsigned long long)f2bf(v.y) << 16)
                        | ((unsigned long long)f2bf(v.z) << 32)
                        | ((unsigned long long)f2bf(v.w) << 48);
  *(unsigned long long*)(Abf + (size_t)wid * 256 + lane * 4) = pk;
  float s = v.x + v.y + v.z + v.w;
  #pragma unroll
  for (int o = 32; o > 0; o >>= 1) s += __shfl_down(s, o);
  if (lane == 0) dinv[wid] = 1.0f / sqrtf(s + 2.0f);
}

// ---------- dinv from bf16 integer adjacency (exact) ----------
__global__ __launch_bounds__(256) void k_dinv_bf(const unsigned short* __restrict__ Abf,
                                                 float* __restrict__ dinv, int n, int rows) {
  int wid = (blockIdx.x * 256 + threadIdx.x) >> 6;
  int lane = threadIdx.x & 63;
  if (wid >= rows) return;
  const unsigned short* row = Abf + (size_t)wid * n;
  float s = 0.f;
  for (int j = lane * 2; j < n; j += 128) {
    unsigned u = *(const unsigned*)(row + j);
    s += bf2f((unsigned short)(u & 0xffffu)) + bf2f((unsigned short)(u >> 16));
  }
  #pragma unroll
  for (int o = 32; o > 0; o >>= 1) s += __shfl_down(s, o);
  if (lane == 0) dinv[wid] = 1.0f / sqrtf(s + 2.0f);
}

// ---------- transpose + 3-plane split ALL weights (runs once, tiny) ----------
__global__ __launch_bounds__(256) void k_splitW3(const float* __restrict__ dW0,
                                                 const float* __restrict__ dW,
                                                 const float* __restrict__ uW,
                                                 const float* __restrict__ uWl,
                                                 unsigned short* __restrict__ Wp) {
  int idx = blockIdx.x * 256 + threadIdx.x;
  if (idx >= WTOT) return;
  float v;
  if (idx < WOFF_DW) {                   // dW0^T [48][128]
    int f = idx / 128, kk = idx - f * 128;
    v = dW0[kk * HID + f];
  } else if (idx < WOFF_UW) {            // dW[i]^T [48][64]
    int r = idx - WOFF_DW;
    int i = r / 3072; r -= i * 3072;
    int f = r / 64, kk = r - f * 64;
    v = (kk < HID) ? dW[((size_t)i * HID + kk) * HID + f] : 0.f;
  } else if (idx < WOFF_UWL) {           // uW[i]^T [48][64]
    int r = idx - WOFF_UW;
    int i = r / 3072; r -= i * 3072;
    int f = r / 64, kk = r - f * 64;
    v = (kk < HID) ? uW[((size_t)i * HID + kk) * HID + f] : 0.f;
  } else {                               // uWl^T [112][64]
    int r = idx - WOFF_UWL;
    int f = r / 64, kk = r - f * 64;
    v = (f < DOUT && kk < HID) ? uWl[(size_t)kk * DOUT + f] : 0.f;
  }
  unsigned short h = f2bf(v);
  float r1 = v - bf2f(h);
  unsigned short m = f2bf(r1);
  float r2 = r1 - bf2f(m);
  unsigned short l = f2bf(r2);
  Wp[idx] = h;
  Wp[idx + WTOT] = m;
  Wp[idx + 2 * WTOT] = l;
}

// ---------- wave-independent MFMA GEMM XW = X @ W, 3-plane split, NO LDS/barrier ----------
template<int KS2>   // K-steps of 32; KP = KS2*32
__global__ __launch_bounds__(256) void k_xws(const float* __restrict__ X,
                                             const unsigned short* __restrict__ Wp,
                                             float* __restrict__ XW,
                                             const float* __restrict__ dinv,
                                             unsigned short* __restrict__ Yth,
                                             unsigned short* __restrict__ Ytl,
                                             int K, int F, int Fpad, int nShift) {
  constexpr int KP = KS2 * 32;
  int mt = (blockIdx.x * 256 + threadIdx.x) >> 6;
  int lane = threadIdx.x & 63;
  int r = lane & 15, q = lane >> 4;
  const float* xr = X + ((long)mt * 16 + r) * K;
  bf16x8_t ah[KS2], am[KS2], al[KS2];
  #pragma unroll
  for (int ks = 0; ks < KS2; ks++) {
    int col0 = ks * 32 + q * 8;
    float v[8];
    if (col0 + 8 <= K) {
      float4 a = *(const float4*)(xr + col0);
      float4 b = *(const float4*)(xr + col0 + 4);
      v[0] = a.x; v[1] = a.y; v[2] = a.z; v[3] = a.w;
      v[4] = b.x; v[5] = b.y; v[6] = b.z; v[7] = b.w;
    } else {
      #pragma unroll
      for (int j = 0; j < 8; j++) v[j] = (col0 + j < K) ? xr[col0 + j] : 0.f;
    }
    #pragma unroll
    for (int j = 0; j < 8; j++) {
      unsigned short h = f2bf(v[j]);
      float r1 = v[j] - bf2f(h);
      unsigned short m = f2bf(r1);
      float r2 = r1 - bf2f(m);
      unsigned short l = f2bf(r2);
      ah[ks][j] = (short)h;
      am[ks][j] = (short)m;
      al[ks][j] = (short)l;
    }
  }
  long row0 = (long)mt * 16 + q * 4;
  float4 dv4 = {0.f, 0.f, 0.f, 0.f};
  long ytBase = 0;
  if (Yth) {
    dv4 = *(const float4*)(dinv + row0);
    int bb = (int)(row0 >> nShift);
    int jj = (int)(row0 & ((1 << nShift) - 1));
    ytBase = (long)bb * Fpad;
    ytBase = ytBase << nShift;
    ytBase += jj;
  }
  int nFT = Fpad >> 4;
  for (int ft = 0; ft < nFT; ft++) {
    int fl = ft * 16 + r;
    const unsigned short* wb = Wp + (size_t)fl * KP + q * 8;
    f32x4_t acc = {0.f, 0.f, 0.f, 0.f};
    #pragma unroll
    for (int ks = 0; ks < KS2; ks++) {
      bf16x8_t bh = *(const bf16x8_t*)(wb + ks * 32);
      bf16x8_t bm = *(const bf16x8_t*)(wb + WTOT + ks * 32);
      bf16x8_t bl = *(const bf16x8_t*)(wb + 2 * WTOT + ks * 32);
      acc = __builtin_amdgcn_mfma_f32_16x16x32_bf16(ah[ks], bh, acc, 0, 0, 0);
      acc = __builtin_amdgcn_mfma_f32_16x16x32_bf16(ah[ks], bm, acc, 0, 0, 0);
      acc = __builtin_amdgcn_mfma_f32_16x16x32_bf16(am[ks], bh, acc, 0, 0, 0);
      acc = __builtin_amdgcn_mfma_f32_16x16x32_bf16(am[ks], bm, acc, 0, 0, 0);
      acc = __builtin_amdgcn_mfma_f32_16x16x32_bf16(ah[ks], bl, acc, 0, 0, 0);
      acc = __builtin_amdgcn_mfma_f32_16x16x32_bf16(al[ks], bh, acc, 0, 0, 0);
    }
    int f = fl;
    if (f < F) {
      if (XW) {
        #pragma unroll
        for (int reg = 0; reg < 4; reg++) XW[(row0 + reg) * F + f] = acc[reg];
      }
      if (Yth) {
        float dvv[4] = {dv4.x, dv4.y, dv4.z, dv4.w};
        unsigned long long hpk = 0, lpk = 0;
        #pragma unroll
        for (int reg = 0; reg < 4; reg++) {
          float v = dvv[reg] * acc[reg];
          unsigned short hi = f2bf(v);
          unsigned short lo = f2bf(v - bf2f(hi));
          hpk |= ((unsigned long long)hi) << (16 * reg);
          lpk |= ((unsigned long long)lo) << (16 * reg);
        }
        long o = ytBase + ((long)f << nShift);
        *(unsigned long long*)(Yth + o) = hpk;
        *(unsigned long long*)(Ytl + o) = lpk;
      }
    }
  }
}

// ---------- LDS-free fused GCN: ITP it-tiles per wave, A in regs ----------
template<int KS, int ITP>
__global__ __launch_bounds__(256) void k_gcn2(
    const unsigned short* __restrict__ Abf, const float* __restrict__ dinv,
    const unsigned short* __restrict__ Yth, const unsigned short* __restrict__ Ytl,
    const float* __restrict__ bias, float* __restrict__ out,
    int F, int Fpad, int dorelu) {
  constexpr int n = KS * 32;
  int b = blockIdx.x & (BATCH - 1);
  int sub = blockIdx.x >> 8;
  int wave = threadIdx.x >> 6, lane = threadIdx.x & 63;
  int r = lane & 15, q = lane >> 4;
  const float* dv = dinv + (size_t)b * n;
  int itBase = (sub * 4 + wave) * ITP;
  bf16x8_t af[ITP][KS];
  #pragma unroll
  for (int l = 0; l < ITP; l++) {
    const unsigned short* ap = Abf + ((size_t)b * n + (itBase + l) * 16 + r) * n + q * 8;
    #pragma unroll
    for (int ks = 0; ks < KS; ks++) af[l][ks] = *(const bf16x8_t*)(ap + ks * 32);
  }
  float di[ITP][4];
  #pragma unroll
  for (int l = 0; l < ITP; l++) {
    int i0 = (itBase + l) * 16 + q * 4;
    #pragma unroll
    for (int reg = 0; reg < 4; reg++) di[l][reg] = dv[i0 + reg];
  }
  int nFT = Fpad >> 4;
  for (int ft = 0; ft < nFT; ft++) {
    int fl = ft * 16 + r;
    const unsigned short* yrowh = Yth + ((size_t)b * Fpad + fl) * n;
    const unsigned short* yrowl = Ytl + ((size_t)b * Fpad + fl) * n;
    f32x4_t acc[ITP];
    #pragma unroll
    for (int l = 0; l < ITP; l++) acc[l] = (f32x4_t){0.f, 0.f, 0.f, 0.f};
    #pragma unroll
    for (int ks = 0; ks < KS; ks++) {
      bf16x8_t bh = *(const bf16x8_t*)(yrowh + q * 8 + ks * 32);
      bf16x8_t bl = *(const bf16x8_t*)(yrowl + q * 8 + ks * 32);
      #pragma unroll
      for (int l = 0; l < ITP; l++) {
        acc[l] = __builtin_amdgcn_mfma_f32_16x16x32_bf16(af[l][ks], bh, acc[l], 0, 0, 0);
        acc[l] = __builtin_amdgcn_mfma_f32_16x16x32_bf16(af[l][ks], bl, acc[l], 0, 0, 0);
      }
    }
    if (fl < F) {
      float bf = bias[fl];
      #pragma unroll
      for (int l = 0; l < ITP; l++) {
        int i0 = (itBase + l) * 16 + q * 4;
        unsigned long long hq = *(const unsigned long long*)(yrowh + i0);
        unsigned long long lq = *(const unsigned long long*)(yrowl + i0);
        #pragma unroll
        for (int reg = 0; reg < 4; reg++) {
          float yv = bf2f((unsigned short)(hq >> (16 * reg)))
                   + bf2f((unsigned short)(lq >> (16 * reg)));
          float v = di[l][reg] * acc[l][reg] + 2.f * di[l][reg] * yv + bf;
          if (dorelu) v = fmaxf(v, 0.f);
          out[((size_t)b * n + i0 + reg) * F + fl] = v;
        }
      }
    }
  }
}

// ---------- fused final-GCN tail: col-96 scores + top-30 rank + top-30 rows (MFMA) ----------
__global__ __launch_bounds__(512) void k_htail(const unsigned short* __restrict__ Abf,
                                               const float* __restrict__ dinv,
                                               const unsigned short* __restrict__ Yth,
                                               const unsigned short* __restrict__ Ytl,
                                               const float* __restrict__ ubl,
                                               float* __restrict__ sp) {
  int b = blockIdx.x, t = threadIdx.x;
  __shared__ float sy[256];
  __shared__ float sc[256];
  __shared__ int sord[32];
  const unsigned short* yh = Yth + ((size_t)b * 112 + 96) * 256;
  const unsigned short* yl = Ytl + ((size_t)b * 112 + 96) * 256;
  if (t < 256) sy[t] = bf2f(yh[t]) + bf2f(yl[t]);
  __syncthreads();
  // col scores: 2 lanes per node
  {
    int i = t >> 1, sub = t & 1;
    const unsigned short* ar = Abf + ((size_t)b * 256 + i) * 256 + sub * 128;
    const float* syp = sy + sub * 128;
    float s = 0.f;
    for (int j = 0; j < 128; j += 2) {
      unsigned u = *(const unsigned*)(ar + j);
      s += bf2f((unsigned short)(u & 0xffffu)) * syp[j]
         + bf2f((unsigned short)(u >> 16)) * syp[j + 1];
    }
    s += __shfl_xor(s, 1);
    if (sub == 0) {
      float d = dinv[(size_t)b * 256 + i];
      sc[i] = d * s + 2.f * d * sy[i];
    }
  }
  __syncthreads();
  // exact top-30 rank: 2 lanes per node
  {
    int i = t >> 1, sub = t & 1;
    float v = sc[i];
    int r = 0;
    int j0 = sub * 128;
    for (int j = j0; j < j0 + 128; j++) {
      float u = sc[j];
      r += (u > v) || (u == v && j < i);
    }
    r += __shfl_xor(r, 1);
    if (sub == 0 && r < 30) sord[r] = i;
  }
  __syncthreads();
  // top-30 rows via gathered-A MFMA: 8 waves = (it 0..1) x (fh 0..3)
  int wave = t >> 6, lane = t & 63;
  int it = wave & 1, fh = wave >> 1;
  int r = lane & 15, q = lane >> 4;
  int ari = it * 16 + r;
  int arow = sord[ari < 30 ? ari : 0];
  const unsigned short* ap = Abf + ((size_t)b * 256 + arow) * 256 + q * 8;
  bf16x8_t af[8];
  #pragma unroll
  for (int ks = 0; ks < 8; ks++) af[ks] = *(const bf16x8_t*)(ap + ks * 32);
  int ftBeg = fh * 2, ftEnd = fh * 2 + 2;
  if (ftEnd > 7) ftEnd = 7;
  for (int ft = ftBeg; ft < ftEnd; ft++) {
    int fl = ft * 16 + r;
    const unsigned short* yrowh = Yth + ((size_t)b * 112 + fl) * 256;
    const unsigned short* yrowl = Ytl + ((size_t)b * 112 + fl) * 256;
    f32x4_t acc = {0.f, 0.f, 0.f, 0.f};
    #pragma unroll
    for (int ks = 0; ks < 8; ks++) {
      bf16x8_t bh = *(const bf16x8_t*)(yrowh + q * 8 + ks * 32);
      bf16x8_t bl = *(const bf16x8_t*)(yrowl + q * 8 + ks * 32);
      acc = __builtin_amdgcn_mfma_f32_16x16x32_bf16(af[ks], bh, acc, 0, 0, 0);
      acc = __builtin_amdgcn_mfma_f32_16x16x32_bf16(af[ks], bl, acc, 0, 0, 0);
    }
    if (fl < DOUT) {
      float bf = ubl[fl];
      #pragma unroll
      for (int reg = 0; reg < 4; reg++) {
        int rowidx = it * 16 + q * 4 + reg;
        if (rowidx < 30) {
          int node = sord[rowidx];
          float d = dinv[(size_t)b * 256 + node];
          float yv = bf2f(yrowh[node]) + bf2f(yrowl[node]);
          sp[((size_t)b * 30 + rowidx) * DOUT + fl] = d * acc[reg] + 2.f * d * yv + bf;
        }
      }
    }
  }
}

// ---------- MFMA augment via M=A+I trick (EXACT), XCD-swizzled ----------
__global__ __launch_bounds__(256) void k_aug_mfma(const unsigned short* __restrict__ Abf,
                                                  const int* __restrict__ perm,
                                                  float* __restrict__ Ap,
                                                  unsigned short* __restrict__ Apbf,
                                                  int n, int k) {
  int kt = k >> 4;
  int inner = blockIdx.x & 255;
  int slot = blockIdx.x >> 8;
  int b = ((inner & 7) << 5) | (inner >> 3);
  int wave = threadIdx.x >> 6, lane = threadIdx.x & 63;
  int tile = slot * 4 + wave;
  int it = tile / kt, ft = tile - it * kt;
  int r = lane & 15, q = lane >> 4;
  const int* pm = perm + (size_t)b * k;
  int rowA = pm[it * 16 + r];
  int rowB = pm[ft * 16 + r];
  const unsigned short* Ab = Abf + (size_t)b * n * n;
  const unsigned short* pa = Ab + (size_t)rowA * n + q * 8;
  const unsigned short* pb = Ab + (size_t)rowB * n + q * 8;
  f32x4_t acc = {0.f, 0.f, 0.f, 0.f};
  for (int k0 = 0; k0 < n; k0 += 32) {
    bf16x8_t a  = *(const bf16x8_t*)(pa + k0);
    bf16x8_t bv = *(const bf16x8_t*)(pb + k0);
    int daA = rowA - k0 - q * 8;
    int daB = rowB - k0 - q * 8;
    #pragma unroll
    for (int e = 0; e < 8; e++) {
      if (daA == e) a[e] = (short)0x3F80;   // bf16(1.0)
      if (daB == e) bv[e] = (short)0x3F80;
    }
    acc = __builtin_amdgcn_mfma_f32_16x16x32_bf16(a, bv, acc, 0, 0, 0);
  }
  int c = ft * 16 + r;
  #pragma unroll
  for (int reg = 0; reg < 4; reg++) {
    int rr = it * 16 + q * 4 + reg;
    float v = acc[reg];
    if (rr == c) v = 0.f;
    if (Ap)   Ap[((size_t)b * k + rr) * k + c] = v;
    if (Apbf) Apbf[((size_t)b * k + rr) * k + c] = f2bf(v);
  }
}

// ---------- fused pooling: score + exact top-k rank + gather (level 0) ----------
__global__ __launch_bounds__(256) void k_pool(const float* __restrict__ H,
                                              const float* __restrict__ p,
                                              int* __restrict__ perm,
                                              float* __restrict__ Hout,
                                              int n, int k) {
  int b = blockIdx.x, t = threadIdx.x;
  __shared__ float s[256];
  __shared__ int sord[128];
  float pn = 0.f;
  #pragma unroll
  for (int j = 0; j < HID; j++) pn += p[j] * p[j];
  if (t < n) {
    const float* hr = H + ((size_t)b * n + t) * HID;
    float acc = 0.f;
    #pragma unroll
    for (int j = 0; j < HID; j++) acc += hr[j] * p[j];
    s[t] = tanhf(acc / sqrtf(pn));
  }
  __syncthreads();
  if (t < n) {
    float v = s[t];
    int r = 0;
    for (int j = 0; j < n; j++) {
      float u = s[j];
      r += (u > v) || (u == v && j < t);
    }
    if (r < k) { perm[(size_t)b * k + r] = t; sord[r] = t; }
  }
  __syncthreads();
  for (int idx = t; idx < k * HID; idx += 256) {
    int r = idx / HID, f = idx - r * HID;
    int pi = sord[r];
    Hout[((size_t)b * k + r) * HID + f] = H[((size_t)b * n + pi) * HID + f] * s[pi];
  }
}

// ---------- decoder scatter-add (outer level only) ----------
__global__ __launch_bounds__(256) void k_scatter(const int* __restrict__ perm,
                                                 const float* __restrict__ Hsrc,
                                                 float* __restrict__ Hdst,
                                                 int n, int k, int total) {
  int idx = blockIdx.x * 256 + threadIdx.x;
  if (idx >= total) return;
  int f = idx % HID;
  int r = (idx / HID) % k;
  int b = idx / (HID * k);
  int pi = perm[(size_t)b * k + r];
  Hdst[((size_t)b * n + pi) * HID + f] += Hsrc[idx];
}

// ---------- fused head (reads precomputed sp[b][30][97]) ----------
__global__ __launch_bounds__(256) void k_head2(const float* __restrict__ spg,
                                               const float* __restrict__ c1W,
                                               const float* __restrict__ c1b,
                                               const float* __restrict__ c2W,
                                               const float* __restrict__ c2b,
                                               const float* __restrict__ oW,
                                               const float* __restrict__ ob,
                                               float* __restrict__ out) {
  int b = blockIdx.x, t = threadIdx.x;
  __shared__ float sp[30 * 97];
  __shared__ float y1[16 * 30];
  __shared__ float yp[16 * 15];
  __shared__ float yc[32 * 11];
  const float* spb = spg + (size_t)b * 30 * 97;
  for (int idx = t; idx < 30 * 97; idx += 256) sp[idx] = spb[idx];
  __syncthreads();
  for (int idx = t; idx < 16 * 30; idx += 256) {
    int c = idx / 30, kk = idx - c * 30;
    float a = c1b[c];
    for (int d = 0; d < 97; d++) a += sp[kk * 97 + d] * c1W[c * 97 + d];
    y1[c * 30 + kk] = fmaxf(a, 0.f);
  }
  __syncthreads();
  for (int idx = t; idx < 16 * 15; idx += 256) {
    int c = idx / 15, t2 = idx - c * 15;
    yp[idx] = fmaxf(y1[c * 30 + 2 * t2], y1[c * 30 + 2 * t2 + 1]);
  }
  __syncthreads();
  for (int idx = t; idx < 32 * 11; idx += 256) {
    int o = idx / 11, t3 = idx - o * 11;
    float a = c2b[o];
    for (int i2 = 0; i2 < 16; i2++)
      for (int w = 0; w < 5; w++)
        a += yp[i2 * 15 + t3 + w] * c2W[(o * 16 + i2) * 5 + w];
    yc[o * 11 + t3] = fmaxf(a, 0.f);
  }
  __syncthreads();
  if (t < 32) {
    float a = ob[t];
    for (int q = 0; q < 352; q++) a += yc[q] * oW[q * 32 + t];
    out[(size_t)b * 32 + t] = fmaxf(a, 0.f);
  }
}

// ========== fused inner U-Net (encoder lvl1..3 + decoder j=3..2 + scatter into H1) ==========
// One block per batch (grid=256 -> 1 block/CU), 512 threads.
// v2: aug1 runs on MFMA (M=A+I trick, fragments gathered straight from global Abf1 —
// no LDS staging, no 4-way-conflict unpack dot); all score/rank/dinv loops are
// lanes-per-row chunked + shfl_xor reduced so all 8 waves stay busy.

__device__ inline void xw_dphase(const float* hin, const float* W, const float* dv,
                                 float* xwd, int n, int t) {
  // xwd[j*48+f] = dv[j] * sum_g hin[j*48+g] * W[g*48+f]
  for (int idx = t; idx < n * 48; idx += 512) {
    int j = idx / 48, f = idx - j * 48;
    const float* hr = hin + j * 48;
    float a = 0.f;
    #pragma unroll
    for (int g = 0; g < 48; g++) a += hr[g] * W[g * 48 + f];
    xwd[idx] = dv[j] * a;
  }
}

__device__ inline void anxw_phase(const float* A, int lda, const float* xwd,
                                  const float* dv, const float* bias,
                                  float* hout, int n, int t) {
  // hout[i][f] = relu(d_i * sum_j A[i][j]*xwd[j][f] + 2*d_i*xwd[i][f] + bias[f])
  for (int idx = t; idx < n * 48; idx += 512) {
    int i = idx / 48, f = idx - i * 48;
    const float* ar = A + i * lda;
    float acc = 0.f;
    #pragma unroll 4
    for (int j = 0; j < n; j++) acc += ar[j] * xwd[j * 48 + f];
    float di = dv[i];
    float v = di * acc + 2.f * di * xwd[i * 48 + f] + bias[f];
    hout[idx] = fmaxf(v, 0.f);
  }
}

// chunked pool: scores + exact rank + gather, LPR = 512/N lanes per row
template<int N, int K>
__device__ inline void pool_phaseT(const float* h, const float* p,
                                   float* sS, int* perm, float* hin, int t) {
  constexpr int LPR = 512 / N;
  int row = t / LPR, sub = t % LPR;
  float pn = 0.f;
  #pragma unroll
  for (int g = 0; g < 48; g++) pn += p[g] * p[g];
  const float* hr = h + row * 48;
  float acc = 0.f;
  for (int g = sub; g < 48; g += LPR) acc += hr[g] * p[g];
  acc = grp_sum<LPR>(acc);
  if (sub == 0) sS[row] = tanhf(acc / sqrtf(pn));
  __syncthreads();
  {
    float v = sS[row];
    int r = 0;
    for (int j = sub; j < N; j += LPR) {
      float u = sS[j];
      r += (u > v) || (u == v && j < row);
    }
    r = grp_isum<LPR>(r);
    if (sub == 0 && r < K) perm[r] = row;
  }
  __syncthreads();
  for (int idx = t; idx < K * 48; idx += 512) {
    int r = idx / 48, g = idx - r * 48;
    int pi = perm[r];
    hin[idx] = h[pi * 48 + g] * sS[pi];
  }
  __syncthreads();
}

// augment (fp32 dot) + chunked dinv, output KK x KK from NN x NN
template<int NN, int KK>
__device__ inline void aug_phaseT(const float* A, int lda, const int* perm,
                                  float* Ao, int ldo, float* dout, int t) {
  for (int idx = t; idx < KK * KK; idx += 512) {
    int r = idx / KK, c = idx - r * KK;
    int pr = perm[r], pc = perm[c];
    const float* ra = A + pr * lda;
    const float* rc = A + pc * lda;
    float acc = 0.f;
    #pragma unroll 4
    for (int j = 0; j < NN; j++) acc += ra[j] * rc[j];
    float v = acc + 2.f * ra[pc];
    Ao[r * ldo + c] = (r == c) ? 0.f : v;
  }
  __syncthreads();
  {
    constexpr int LPR = 512 / KK;
    int row = t / LPR, sub = t % LPR;
    float s = 0.f;
    for (int j = sub; j < KK; j += LPR) s += Ao[row * ldo + j];
    s = grp_sum<LPR>(s);
    if (sub == 0) dout[row] = 1.0f / sqrtf(s + 2.0f);
  }
  __syncthreads();
}

__device__ inline void scat_phase(const int* perm, const float* src, float* dst,
                                  int k, int t) {
  for (int idx = t; idx < k * 48; idx += 512) {
    int r = idx / 48, g = idx - r * 48;
    dst[perm[r] * 48 + g] += src[idx];
  }
  __syncthreads();
}

__global__ __launch_bounds__(512) void k_inner(const unsigned short* __restrict__ Abf1g,
                                               float* __restrict__ H1g,
                                               const float* __restrict__ dW,
                                               const float* __restrict__ dbv,
                                               const float* __restrict__ pp,
                                               const float* __restrict__ uW,
                                               const float* __restrict__ ub) {
  int b = blockIdx.x, t = threadIdx.x;
  const unsigned short* A1 = Abf1g + (size_t)b * 128 * 128;
  float* H1 = H1g + (size_t)b * 128 * 48;

  __shared__ float sS[128];
  __shared__ int   sP2[64], sP3[32], sP4[16];
  __shared__ float sD2[64], sD3[32], sD4[16];
  __shared__ float sA2[64 * 65];
  __shared__ float sA3[32 * 33];
  __shared__ float sH2[64 * 48];   // xs[2] residual, updated in place by decoder
  __shared__ float sH3[32 * 48];   // xs[3] residual
  __shared__ float sU[6144];       // union scratch
  float* hin = sU;                 // pooled input [n][48], n<=64
  float* sXW = sU + 3072;          // d-scaled XW [n][48]
  float* sH4 = sU + 1536;          // [16][48]  (hin only occupies [0,768) at lvl3)
  float* sA4 = sU + 2304;          // [16][17]

  // ===== encoder level 1 pool: scores + rank over H1 (n=128 -> k=64), LPR=4 =====
  {
    const float* p = pp + 48;
    float pn = 0.f;
    #pragma unroll
    for (int g = 0; g < 48; g++) pn += p[g] * p[g];
    int row = t >> 2, sub = t & 3;
    const float* hr = H1 + row * 48;
    float acc = 0.f;
    for (int g = sub; g < 48; g += 4) acc += hr[g] * p[g];
    acc = grp_sum<4>(acc);
    if (sub == 0) sS[row] = tanhf(acc / sqrtf(pn));
    __syncthreads();
    float v = sS[row];
    int rk = 0;
    for (int j = sub; j < 128; j += 4) {
      float u = sS[j];
      rk += (u > v) || (u == v && j < row);
    }
    rk = grp_isum<4>(rk);
    if (sub == 0 && rk < 64) sP2[rk] = row;
    __syncthreads();
  }

  // ===== aug1 on MFMA: A2 = (A1+I)^2 off-diag (exact: integer bf16 inputs) =====
  // 16 tiles of 16x16 (K=128), 2 per wave; fragments gathered from global A1.
  {
    int wave = t >> 6, lane = t & 63;
    int r = lane & 15, q = lane >> 4;
    #pragma unroll
    for (int tt = 0; tt < 2; tt++) {
      int tile = wave * 2 + tt;
      int it = tile >> 2, ft = tile & 3;
      int rowA = sP2[it * 16 + r];
      int rowB = sP2[ft * 16 + r];
      const unsigned short* pa = A1 + (size_t)rowA * 128 + q * 8;
      const unsigned short* pb = A1 + (size_t)rowB * 128 + q * 8;
      f32x4_t acc = {0.f, 0.f, 0.f, 0.f};
      #pragma unroll
      for (int k0 = 0; k0 < 128; k0 += 32) {
        bf16x8_t a  = *(const bf16x8_t*)(pa + k0);
        bf16x8_t bv = *(const bf16x8_t*)(pb + k0);
        int daA = rowA - k0 - q * 8;
        int daB = rowB - k0 - q * 8;
        #pragma unroll
        for (int e = 0; e < 8; e++) {
          if (daA == e) a[e] = (short)0x3F80;   // bf16(1.0) diag patch
          if (daB == e) bv[e] = (short)0x3F80;
        }
        acc = __builtin_amdgcn_mfma_f32_16x16x32_bf16(a, bv, acc, 0, 0, 0);
      }
      int c = ft * 16 + r;
      #pragma unroll
      for (int reg = 0; reg < 4; reg++) {
        int rr = it * 16 + q * 4 + reg;
        sA2[rr * 65 + c] = (rr == c) ? 0.f : acc[reg];
      }
    }
    // gather pooled input (independent of sA2 writes)
    for (int idx = t; idx < 64 * 48; idx += 512) {
      int r2 = idx / 48, g = idx - r2 * 48;
      int pi = sP2[r2];
      hin[idx] = H1[pi * 48 + g] * sS[pi];
    }
  }
  __syncthreads();
  // D2 rowsum (LPR=8)
  {
    int row = t >> 3, sub = t & 7;
    float s = 0.f;
    for (int j = sub; j < 64; j += 8) s += sA2[row * 65 + j];
    s = grp_sum<8>(s);
    if (sub == 0) sD2[row] = 1.0f / sqrtf(s + 2.0f);
  }
  __syncthreads();
  // encoder GCN level 1 (dW[1], db[1]) -> sH2 (= xs[2])
  xw_dphase(hin, dW + 2304, sD2, sXW, 64, t);
  __syncthreads();
  anxw_phase(sA2, 65, sXW, sD2, dbv + 48, sH2, 64, t);
  __syncthreads();

  // ===== encoder level 2 (64 -> 32): dW[2], db[2], pool_p[2] =====
  pool_phaseT<64, 32>(sH2, pp + 96, sS, sP3, hin, t);
  aug_phaseT<64, 32>(sA2, 65, sP3, sA3, 33, sD3, t);
  xw_dphase(hin, dW + 2 * 2304, sD3, sXW, 32, t);
  __syncthreads();
  anxw_phase(sA3, 33, sXW, sD3, dbv + 96, sH3, 32, t);
  __syncthreads();

  // ===== encoder level 3 (32 -> 16): dW[3], db[3], pool_p[3] =====
  pool_phaseT<32, 16>(sH3, pp + 144, sS, sP4, hin, t);
  aug_phaseT<32, 16>(sA3, 33, sP4, sA4, 17, sD4, t);
  xw_dphase(hin, dW + 3 * 2304, sD4, sXW, 16, t);
  __syncthreads();
  anxw_phase(sA4, 17, sXW, sD4, dbv + 144, sH4, 16, t);
  __syncthreads();

  // ===== decoder j=3: sH3 += up(sH4); GCN(uW[0], ub[0], A3/D3) =====
  scat_phase(sP4, sH4, sH3, 16, t);
  xw_dphase(sH3, uW, sD3, sXW, 32, t);
  __syncthreads();
  anxw_phase(sA3, 33, sXW, sD3, ub, sH3, 32, t);
  __syncthreads();

  // ===== decoder j=2: sH2 += up(sH3); GCN(uW[1], ub[1], A2/D2) =====
  scat_phase(sP3, sH3, sH2, 32, t);
  xw_dphase(sH2, uW + 2304, sD2, sXW, 64, t);
  __syncthreads();
  anxw_phase(sA2, 65, sXW, sD2, ub + 48, sH2, 64, t);
  __syncthreads();

  // ===== final: H1 (global) += up(sH2) via P2 =====
  for (int idx = t; idx < 64 * 48; idx += 512) {
    int r2 = idx / 48, g = idx - r2 * 48;
    H1[sP2[r2] * 48 + g] += sH2[idx];
  }
}

extern "C" void kernel_launch(void* const* d_in, const int* in_sizes, int n_in,
                              void* d_out, int out_size, void* d_ws, size_t ws_size,
                              hipStream_t stream) {
  const float* x   = (const float*)d_in[0];
  const float* A0  = (const float*)d_in[1];
  const float* dW0 = (const float*)d_in[2];
  const float* db0 = (const float*)d_in[3];
  const float* dW  = (const float*)d_in[4];
  const float* dbv = (const float*)d_in[5];
  const float* pp  = (const float*)d_in[6];
  const float* uW  = (const float*)d_in[7];
  const float* ub  = (const float*)d_in[8];
  const float* uWl = (const float*)d_in[9];
  const float* ubl = (const float*)d_in[10];
  const float* c1W = (const float*)d_in[11];
  const float* c1b = (const float*)d_in[12];
  const float* c2W = (const float*)d_in[13];
  const float* c2b = (const float*)d_in[14];
  const float* oW  = (const float*)d_in[15];
  const float* ob  = (const float*)d_in[16];
  float* out = (float*)d_out;

  float* base = (float*)d_ws;
  size_t off = 0;
  auto alloc = [&](size_t nel) { nel = (nel + 3) & ~(size_t)3; float* p = base + off; off += nel; return p; };
  float* H0 = alloc((size_t)BATCH * 256 * HID);
  float* H1 = alloc((size_t)BATCH * 128 * HID);
  float* D0 = alloc((size_t)BATCH * 256);
  float* D1 = alloc((size_t)BATCH * 128);
  float* SP  = alloc((size_t)BATCH * 30 * 97);
  int* P1 = (int*)alloc((size_t)BATCH * 128);
  unsigned short* Abf0 = (unsigned short*)alloc((size_t)BATCH * 256 * 256 / 2);
  unsigned short* Abf1 = (unsigned short*)alloc((size_t)BATCH * 128 * 128 / 2);
  unsigned short* Yth  = (unsigned short*)alloc((size_t)BATCH * 112 * 256 / 2);
  unsigned short* Ytl  = (unsigned short*)alloc((size_t)BATCH * 112 * 256 / 2);
  unsigned short* Wp   = (unsigned short*)alloc((size_t)3 * WTOT / 2 + 4);

  // ---- prologue ----
  k_prepA<<<BATCH * 256 / 4, 256, 0, stream>>>(A0, Abf0, D0, BATCH * 256);
  k_splitW3<<<(WTOT + 255) / 256, 256, 0, stream>>>(dW0, dW, uW, uWl, Wp);

  // ---- first GCN (n=256) ----
  k_xws<4><<<BATCH * 256 / 64, 256, 0, stream>>>(x, Wp + WOFF_DW0, nullptr,
                                                 D0, Yth, Ytl, FIN, HID, 48, 8);
  k_gcn2<8, 2><<<BATCH * 2, 256, 0, stream>>>(Abf0, D0, Yth, Ytl, db0, H0, HID, 48, 1);

  // ---- encoder level 0 (256 -> 128, MFMA path) ----
  k_pool<<<BATCH, 256, 0, stream>>>(H0, pp, P1, H1, 256, 128);
  k_aug_mfma<<<16 * 256, 256, 0, stream>>>(Abf0, P1, nullptr, Abf1, 256, 128);
  k_dinv_bf<<<BATCH * 128 / 4, 256, 0, stream>>>(Abf1, D1, 128, BATCH * 128);
  k_xws<2><<<BATCH * 128 / 64, 256, 0, stream>>>(H1, Wp + WOFF_DW, nullptr,
                                                 D1, Yth, Ytl, HID, HID, 48, 7);
  k_gcn2<4, 1><<<BATCH * 2, 256, 0, stream>>>(Abf1, D1, Yth, Ytl, dbv, H1, HID, 48, 1);

  // ---- fused inner U: enc lvl1..3 + dec j=3..2 + scatter into H1 ----
  k_inner<<<BATCH, 512, 0, stream>>>(Abf1, H1, dW, dbv, pp, uW, ub);

  // ---- decoder j=1 (n=128, MFMA path, uW[2], ub[2]) ----
  k_xws<2><<<BATCH * 128 / 64, 256, 0, stream>>>(H1, Wp + WOFF_UW + 2 * 3072, nullptr,
                                                 D1, Yth, Ytl, HID, HID, 48, 7);
  k_gcn2<4, 1><<<BATCH * 2, 256, 0, stream>>>(Abf1, D1, Yth, Ytl, ub + 2 * HID,
                                              H1, HID, 48, 1);

  // ---- decoder j=0: scatter + final GCN (fused col-96 + rank + top-30 rows) ----
  k_scatter<<<(BATCH * 128 * HID + 255) / 256, 256, 0, stream>>>(P1, H1, H0,
                                                                 256, 128, BATCH * 128 * HID);
  k_xws<2><<<BATCH * 256 / 64, 256, 0, stream>>>(H0, Wp + WOFF_UWL, nullptr,
                                                 D0, Yth, Ytl, HID, DOUT, 112, 8);
  k_htail<<<BATCH, 512, 0, stream>>>(Abf0, D0, Yth, Ytl, ubl, SP);

  // ---- fused head ----
  k_head2<<<BATCH, 256, 0, stream>>>(SP, c1W, c1b, c2W, c2b, oW, ob, out);
}